// Round 5
// baseline (168.846 us; speedup 1.0000x reference)
//
#include <hip/hip_runtime.h>

#define TSEQ 2048
#define DDIM 1024
#define HSZ  64
#define NB   4
#define NROWS (NB * TSEQ)

typedef short bf16x8 __attribute__((ext_vector_type(8)));
typedef short s16x4  __attribute__((ext_vector_type(4)));
typedef float f32x4  __attribute__((ext_vector_type(4)));
typedef unsigned int u32;
typedef unsigned int u32x4 __attribute__((ext_vector_type(4)));

#define MFMA16(a, b, c) __builtin_amdgcn_mfma_f32_16x16x32_bf16((a), (b), (c), 0, 0, 0)

// Split fp32 into bf16 hi (round-to-nearest-even) + bf16 lo (exact residual, truncated).
__device__ inline void split_rn(float f, short& hi, short& lo) {
    u32 u = __builtin_bit_cast(u32, f);
    u32 rr = (u + 0x7fffu + ((u >> 16) & 1u)) & 0xffff0000u;
    hi = (short)(rr >> 16);
    float fh = __builtin_bit_cast(float, rr);
    float fl = f - fh;
    lo = (short)(__builtin_bit_cast(u32, fl) >> 16);
}

// ---------------------------------------------------------------------------
// Kernel 0: split W (fp32 [3*64][1024]) -> bf16 hi/lo [192][1024] (plain layout).
// ---------------------------------------------------------------------------
__global__ __launch_bounds__(256) void wsplit_kernel(
    const float* __restrict__ Wk, const float* __restrict__ Wq, const float* __restrict__ Wv,
    short* __restrict__ wbhi, short* __restrict__ wblo)
{
    int i = blockIdx.x * 256 + threadIdx.x;      // 49152 threads, 4 floats each
    int off = i << 2;                            // flat elem in [192][1024]
    int which = off >> 16;
    int loc = off & 65535;
    const float* src = (which == 0) ? Wk : (which == 1) ? Wq : Wv;
    float4 v = *(const float4*)(src + loc);
    short h0,h1,h2,h3, l0,l1,l2,l3;
    split_rn(v.x, h0, l0); split_rn(v.y, h1, l1);
    split_rn(v.z, h2, l2); split_rn(v.w, h3, l3);
    *(s16x4*)(wbhi + off) = (s16x4){h0,h1,h2,h3};
    *(s16x4*)(wblo + off) = (s16x4){l0,l1,l2,l3};
}

// ---------------------------------------------------------------------------
// Kernel 1: fused QKV projection, BARRIER-FREE main loop (no W/x LDS staging).
// grid 256, block 512 (8 waves). Block: 32 tokens x 192 cols (k|q|v).
// A-frags read directly from x (fp32 -> split in registers); B-frags read
// directly from wbhi/wblo (L2-hot, 3MB). Wave w: rows (w&1)*16,
// col group (w>>1)*48 (3 col-tiles of 16).
// ---------------------------------------------------------------------------
__global__ __launch_bounds__(512) void proj_mfma(
    const float* __restrict__ x,
    const short* __restrict__ wbhi, const short* __restrict__ wblo,
    short* __restrict__ khi, short* __restrict__ klo,
    short* __restrict__ qhi, short* __restrict__ qlo,
    short* __restrict__ vthi, short* __restrict__ vtlo)
{
    __shared__ __align__(16) short vtrh[64][36], vtrl[64][36];

    const int tid  = threadIdx.x;
    const int w    = tid >> 6;
    const int lane = tid & 63;
    const int g    = lane >> 4;
    const int c    = lane & 15;
    const int rowoff = (w & 1) * 16;
    const int colgrp = w >> 1;                    // 0..3
    const long rb  = (long)blockIdx.x * 32;

    f32x4 acc[3];
    acc[0] = 0; acc[1] = 0; acc[2] = 0;

    const float* xrow = x + (rb + rowoff + c) * DDIM;
    const int wr0 = colgrp * 48 + c;

    #pragma unroll 2
    for (int k0 = 0; k0 < DDIM; k0 += 64) {
        #pragma unroll
        for (int kk = 0; kk < 2; ++kk) {
            const int off = k0 + kk*32 + 8*g;
            float4 xa = *(const float4*)(xrow + off);
            float4 xb = *(const float4*)(xrow + off + 4);
            bf16x8 ah, al;
            {
                short h, lo2;
                split_rn(xa.x, h, lo2); ah[0]=h; al[0]=lo2;
                split_rn(xa.y, h, lo2); ah[1]=h; al[1]=lo2;
                split_rn(xa.z, h, lo2); ah[2]=h; al[2]=lo2;
                split_rn(xa.w, h, lo2); ah[3]=h; al[3]=lo2;
                split_rn(xb.x, h, lo2); ah[4]=h; al[4]=lo2;
                split_rn(xb.y, h, lo2); ah[5]=h; al[5]=lo2;
                split_rn(xb.z, h, lo2); ah[6]=h; al[6]=lo2;
                split_rn(xb.w, h, lo2); ah[7]=h; al[7]=lo2;
            }
            #pragma unroll
            for (int t = 0; t < 3; ++t) {
                const long wofs = (long)(wr0 + t*16) * DDIM + off;
                bf16x8 bh = *(const bf16x8*)(wbhi + wofs);
                bf16x8 bl = *(const bf16x8*)(wblo + wofs);
                acc[t] = MFMA16(al, bh, acc[t]);
                acc[t] = MFMA16(ah, bl, acc[t]);
                acc[t] = MFMA16(ah, bh, acc[t]);
            }
        }
    }

    // epilogue: k/q direct to global; v transposed through small LDS
    const int batch = (int)(rb >> 11);
    const int t0 = (int)(rb & 2047);
    #pragma unroll
    for (int t = 0; t < 3; ++t) {
        int col16 = colgrp * 48 + t * 16;
        int mode = col16 >> 6;
        int lcol = col16 - (mode << 6) + c;
        if (mode < 2) {
            short* oh = mode ? qhi : khi;
            short* ol = mode ? qlo : klo;
            const float sc = mode ? 8.0f : 1.0f;   // fold bug-faithful *sqrt(HS) into q
            #pragma unroll
            for (int r = 0; r < 4; ++r) {
                long row = rb + rowoff + 4*g + r;
                short h, lo2; split_rn(acc[t][r] * sc, h, lo2);
                oh[row * HSZ + lcol] = h;
                ol[row * HSZ + lcol] = lo2;
            }
        } else {
            #pragma unroll
            for (int r = 0; r < 4; ++r) {
                short h, lo2; split_rn(acc[t][r], h, lo2);
                vtrh[lcol][rowoff + 4*g + r] = h;
                vtrl[lcol][rowoff + 4*g + r] = lo2;
            }
        }
    }
    __syncthreads();
    {
        int d = tid >> 3, t4 = (tid & 7) << 2;
        long gofs = ((long)(batch * HSZ + d)) * TSEQ + t0 + t4;
        *(s16x4*)(vthi + gofs) = *(const s16x4*)&vtrh[d][t4];
        *(s16x4*)(vtlo + gofs) = *(const s16x4*)&vtrl[d][t4];
    }
}

// ---------------------------------------------------------------------------
// Kernel 2: causal flash attention, barrier-free main loop, PAIRED q-tiles.
// grid 256 (one tile-PAIR per block: tiles 2u, 2u+1 = 32 q-rows), block 512
// (8 waves). Wave w strides key windows jb = 512s + 64w with per-wave online
// softmax for BOTH tiles; K/V fragment loads are shared between the two
// tiles (halves L2 traffic per MFMA, doubles per-step ILP). Swapped QK^T:
// lane owns q-row c of each tile. Cross-wave merge once at the end.
// Mapping u = 63-(bid>>2), batch = bid&3: each XCD sees ONE batch (K/V L2-
// resident) with interleaved pair weights (balanced).
// ---------------------------------------------------------------------------
__global__ __launch_bounds__(512, 2) void attn_mfma(
    const short* __restrict__ qhi, const short* __restrict__ qlo,
    const short* __restrict__ khi, const short* __restrict__ klo,
    const short* __restrict__ vthi, const short* __restrict__ vtlo,
    float* __restrict__ out)
{
    __shared__ __align__(16) u32 pbuf[8][2][16][68];
    __shared__ float obuf[7][2][16][68];
    __shared__ float mlbuf[8][2][16][2];

    const int tid  = threadIdx.x;
    const int w    = tid >> 6;
    const int lane = tid & 63;
    const int g    = lane >> 4;
    const int c    = lane & 15;

    const int bid   = blockIdx.x;
    const int u     = 63 - (bid >> 2);
    const int batch = bid & 3;
    const int qA0   = u << 5;                  // tile 2u
    const long bb   = (long)batch * TSEQ;
    const int lastkey = qA0 + 31;              // tile 2u+1's last key

    // Q fragments (B-operand of swapped QK^T) for both tiles
    bf16x8 qh[2][2], ql[2][2];                 // [tile][kk]
    #pragma unroll
    for (int tt = 0; tt < 2; ++tt) {
        const long qofs = (bb + qA0 + tt*16 + c) * HSZ;
        #pragma unroll
        for (int kk = 0; kk < 2; ++kk) {
            qh[tt][kk] = *(const bf16x8*)(qhi + qofs + kk*32 + 8*g);
            ql[tt][kk] = *(const bf16x8*)(qlo + qofs + kk*32 + 8*g);
        }
    }

    f32x4 oacc[2][4];
    #pragma unroll
    for (int tt = 0; tt < 2; ++tt)
        #pragma unroll
        for (int dt = 0; dt < 4; ++dt) oacc[tt][dt] = 0;
    float m[2] = {-1e30f, -1e30f}, l[2] = {0.0f, 0.0f};

    if (64 * w <= lastkey) {
        const int nsteps = ((lastkey - 64 * w) >> 9) + 1;
        for (int s = 0; s < nsteps; ++s) {
            const int jb = (s << 9) + (w << 6);
            // ---- K fragment loads (shared by both q-tiles) ----
            bf16x8 kb_h[2][4], kb_l[2][4];     // [kk][t]
            #pragma unroll
            for (int kk = 0; kk < 2; ++kk)
                #pragma unroll
                for (int t = 0; t < 4; ++t) {
                    const long kofs = (bb + jb + t*16 + c) * HSZ + kk*32 + 8*g;
                    kb_h[kk][t] = *(const bf16x8*)(khi + kofs);
                    kb_l[kk][t] = *(const bf16x8*)(klo + kofs);
                }
            // ---- S^T = mfma(K, Q): lane -> S[qrow=c][key=jb+16t+4g+r] ----
            f32x4 sa[2][4];
            #pragma unroll
            for (int tt = 0; tt < 2; ++tt)
                #pragma unroll
                for (int t = 0; t < 4; ++t) sa[tt][t] = 0;
            #pragma unroll
            for (int kk = 0; kk < 2; ++kk)
                #pragma unroll
                for (int t = 0; t < 4; ++t) {
                    #pragma unroll
                    for (int tt = 0; tt < 2; ++tt) {
                        sa[tt][t] = MFMA16(kb_h[kk][t], ql[tt][kk], sa[tt][t]);
                        sa[tt][t] = MFMA16(kb_l[kk][t], qh[tt][kk], sa[tt][t]);
                        sa[tt][t] = MFMA16(kb_h[kk][t], qh[tt][kk], sa[tt][t]);
                    }
                }
            // ---- V fragment loads (prefetch; overlap softmax+LDS) ----
            bf16x8 vb_h[2][4], vb_l[2][4];     // [kk][dt]
            #pragma unroll
            for (int kk = 0; kk < 2; ++kk)
                #pragma unroll
                for (int dt = 0; dt < 4; ++dt) {
                    const long vofs = ((long)(batch * HSZ + dt*16 + c)) * TSEQ + jb + kk*32 + 8*g;
                    vb_h[kk][dt] = *(const bf16x8*)(vthi + vofs);
                    vb_l[kk][dt] = *(const bf16x8*)(vtlo + vofs);
                }
            // ---- causal masks ----
            #pragma unroll
            for (int tt = 0; tt < 2; ++tt) {
                const int q0 = qA0 + tt*16;
                if (jb + 63 > q0) {
                    #pragma unroll
                    for (int t = 0; t < 4; ++t) {
                        const int kb0 = jb + t*16 + 4*g;
                        #pragma unroll
                        for (int r = 0; r < 4; ++r)
                            if (kb0 + r > q0 + c) sa[tt][t][r] = -1e30f;
                    }
                }
            }
            // ---- per-lane online softmax (row c of each tile) ----
            #pragma unroll
            for (int tt = 0; tt < 2; ++tt) {
                float mx = sa[tt][0][0];
                #pragma unroll
                for (int t = 0; t < 4; ++t)
                    #pragma unroll
                    for (int r = 0; r < 4; ++r) mx = fmaxf(mx, sa[tt][t][r]);
                mx = fmaxf(mx, __shfl_xor(mx, 16));
                mx = fmaxf(mx, __shfl_xor(mx, 32));
                const float mn = fmaxf(m[tt], mx);
                float rs = 0.0f;
                #pragma unroll
                for (int t = 0; t < 4; ++t) {
                    #pragma unroll
                    for (int r = 0; r < 4; ++r) {
                        float p = __expf(sa[tt][t][r] - mn);
                        rs += p;
                        short h, lo2; split_rn(p, h, lo2);
                        pbuf[w][tt][c][t*16 + 4*g + r] =
                            (u32)(unsigned short)h | ((u32)(unsigned short)lo2 << 16);
                    }
                }
                rs += __shfl_xor(rs, 16);
                rs += __shfl_xor(rs, 32);
                const float fs = __expf(m[tt] - mn);
                l[tt] = l[tt] * fs + rs;
                m[tt] = mn;
                float fr[4];
                #pragma unroll
                for (int r = 0; r < 4; ++r) fr[r] = __shfl(fs, 20*g + r);
                #pragma unroll
                for (int dt = 0; dt < 4; ++dt) {
                    oacc[tt][dt][0] *= fr[0]; oacc[tt][dt][1] *= fr[1];
                    oacc[tt][dt][2] *= fr[2]; oacc[tt][dt][3] *= fr[3];
                }
            }
            // ---- O += P V (P via per-wave LDS transpose, V already in regs) ----
            #pragma unroll
            for (int kk = 0; kk < 2; ++kk) {
                bf16x8 pah[2], pal[2];
                #pragma unroll
                for (int tt = 0; tt < 2; ++tt) {
                    u32x4 pw0 = *(const u32x4*)&pbuf[w][tt][c][kk*32 + 8*g];
                    u32x4 pw1 = *(const u32x4*)&pbuf[w][tt][c][kk*32 + 8*g + 4];
                    u32x4 th, tl;
                    th[0] = (pw0[0] & 0xffffu) | (pw0[1] << 16);
                    tl[0] = (pw0[0] >> 16)    | (pw0[1] & 0xffff0000u);
                    th[1] = (pw0[2] & 0xffffu) | (pw0[3] << 16);
                    tl[1] = (pw0[2] >> 16)    | (pw0[3] & 0xffff0000u);
                    th[2] = (pw1[0] & 0xffffu) | (pw1[1] << 16);
                    tl[2] = (pw1[0] >> 16)    | (pw1[1] & 0xffff0000u);
                    th[3] = (pw1[2] & 0xffffu) | (pw1[3] << 16);
                    tl[3] = (pw1[2] >> 16)    | (pw1[3] & 0xffff0000u);
                    pah[tt] = __builtin_bit_cast(bf16x8, th);
                    pal[tt] = __builtin_bit_cast(bf16x8, tl);
                }
                #pragma unroll
                for (int dt = 0; dt < 4; ++dt) {
                    #pragma unroll
                    for (int tt = 0; tt < 2; ++tt) {
                        oacc[tt][dt] = MFMA16(pal[tt], vb_h[kk][dt], oacc[tt][dt]);
                        oacc[tt][dt] = MFMA16(pah[tt], vb_l[kk][dt], oacc[tt][dt]);
                        oacc[tt][dt] = MFMA16(pah[tt], vb_h[kk][dt], oacc[tt][dt]);
                    }
                }
            }
        }
    }

    // ---- cross-wave merge (both tiles) ----
    if (lane < 16) {
        #pragma unroll
        for (int tt = 0; tt < 2; ++tt) {
            mlbuf[w][tt][lane][0] = m[tt];
            mlbuf[w][tt][lane][1] = l[tt];
        }
    }
    if (w > 0) {
        #pragma unroll
        for (int tt = 0; tt < 2; ++tt)
            #pragma unroll
            for (int dt = 0; dt < 4; ++dt)
                #pragma unroll
                for (int r = 0; r < 4; ++r)
                    obuf[w-1][tt][4*g + r][dt*16 + c] = oacc[tt][dt][r];
    }
    __syncthreads();
    if (w == 0) {
        #pragma unroll
        for (int tt = 0; tt < 2; ++tt) {
            #pragma unroll
            for (int r = 0; r < 4; ++r) {
                const int row = 4*g + r;
                float ms = mlbuf[0][tt][row][0];
                #pragma unroll
                for (int wv = 1; wv < 8; ++wv) ms = fmaxf(ms, mlbuf[wv][tt][row][0]);
                float ls = 0.0f; float fw[8];
                #pragma unroll
                for (int wv = 0; wv < 8; ++wv) {
                    fw[wv] = __expf(mlbuf[wv][tt][row][0] - ms);
                    ls += mlbuf[wv][tt][row][1] * fw[wv];
                }
                const float linv = 1.0f / ls;
                #pragma unroll
                for (int dt = 0; dt < 4; ++dt) {
                    float val = oacc[tt][dt][r] * fw[0];
                    #pragma unroll
                    for (int wv = 1; wv < 8; ++wv)
                        val += obuf[wv-1][tt][row][dt*16 + c] * fw[wv];
                    out[(bb + qA0 + tt*16 + row) * HSZ + dt*16 + c] = val * linv;
                }
            }
        }
    }
}

// ---------------------------------------------------------------------------
extern "C" void kernel_launch(void* const* d_in, const int* in_sizes, int n_in,
                              void* d_out, int out_size, void* d_ws, size_t ws_size,
                              hipStream_t stream) {
    const float* x  = (const float*)d_in[0];
    const float* Wk = (const float*)d_in[1];
    const float* Wq = (const float*)d_in[2];
    const float* Wv = (const float*)d_in[3];
    float* out = (float*)d_out;

    short* ws = (short*)d_ws;
    const size_t SEG = (size_t)NROWS * HSZ;   // 524288 elements
    short* khi  = ws;
    short* klo  = ws + SEG;
    short* qhi  = ws + 2*SEG;
    short* qlo  = ws + 3*SEG;
    short* vthi = ws + 4*SEG;                 // [4][64][2048]
    short* vtlo = ws + 5*SEG;
    short* wbhi = ws + 6*SEG;                 // [3][64][1024]
    short* wblo = wbhi + 3*HSZ*DDIM;

    wsplit_kernel<<<192, 256, 0, stream>>>(Wk, Wq, Wv, wbhi, wblo);
    proj_mfma<<<256, 512, 0, stream>>>(x, wbhi, wblo, khi, klo, qhi, qlo, vthi, vtlo);
    attn_mfma<<<256, 512, 0, stream>>>(qhi, qlo, khi, klo, vthi, vtlo, out);
}

// Round 6
// 135.615 us; speedup vs baseline: 1.2450x; 1.2450x over previous
//
#include <hip/hip_runtime.h>

#define TSEQ 2048
#define DDIM 1024
#define HSZ  64
#define NB   4
#define NROWS (NB * TSEQ)

typedef short bf16x8 __attribute__((ext_vector_type(8)));
typedef short s16x4  __attribute__((ext_vector_type(4)));
typedef float f32x4  __attribute__((ext_vector_type(4)));
typedef unsigned int u32;

#define MFMA16(a, b, c) __builtin_amdgcn_mfma_f32_16x16x32_bf16((a), (b), (c), 0, 0, 0)

// fp32 -> bf16 hi (RN) + bf16 lo (residual)
__device__ inline void split_rn(float f, short& hi, short& lo) {
    u32 u = __builtin_bit_cast(u32, f);
    u32 rr = (u + 0x7fffu + ((u >> 16) & 1u)) & 0xffff0000u;
    hi = (short)(rr >> 16);
    float fh = __builtin_bit_cast(float, rr);
    float fl = f - fh;
    lo = (short)(__builtin_bit_cast(u32, fl) >> 16);
}
__device__ inline short bf16rn(float f) {
    u32 u = __builtin_bit_cast(u32, f);
    return (short)((u + 0x7fffu + ((u >> 16) & 1u)) >> 16);
}

// ---------------------------------------------------------------------------
// Kernel 0: split W (fp32 [3*64][1024]) -> bf16 hi/lo [192][1024].
// ---------------------------------------------------------------------------
__global__ __launch_bounds__(256) void wsplit_kernel(
    const float* __restrict__ Wk, const float* __restrict__ Wq, const float* __restrict__ Wv,
    short* __restrict__ wbhi, short* __restrict__ wblo)
{
    int i = blockIdx.x * 256 + threadIdx.x;
    int off = i << 2;
    int which = off >> 16;
    int loc = off & 65535;
    const float* src = (which == 0) ? Wk : (which == 1) ? Wq : Wv;
    float4 v = *(const float4*)(src + loc);
    short h0,h1,h2,h3, l0,l1,l2,l3;
    split_rn(v.x, h0, l0); split_rn(v.y, h1, l1);
    split_rn(v.z, h2, l2); split_rn(v.w, h3, l3);
    *(s16x4*)(wbhi + off) = (s16x4){h0,h1,h2,h3};
    *(s16x4*)(wblo + off) = (s16x4){l0,l1,l2,l3};
}

// ---------------------------------------------------------------------------
// Kernel 1: QKV projection, BM=64, grid (128,3), 256 thr (4 waves).
// LDS staged with stride-88 rows (2-way bank aliasing = free), reg-staged
// (global->reg->ds_write) so padding is legal. ~45KB LDS -> 3 blocks/CU.
// Wave w: rows 16w..16w+15, all 64 cols of its mode. v output: bf16 hi only,
// transposed to [4*64][2048].
// ---------------------------------------------------------------------------
__global__ __launch_bounds__(256, 3) void proj_mfma(
    const float* __restrict__ x,
    const short* __restrict__ wbhi, const short* __restrict__ wblo,
    short* __restrict__ khi, short* __restrict__ klo,
    short* __restrict__ qhi, short* __restrict__ qlo,
    short* __restrict__ vthi)
{
    __shared__ __align__(16) short xh[64][88], xl[64][88];
    __shared__ __align__(16) short wh[64][88], wl[64][88];

    const int tid  = threadIdx.x;
    const int wv   = tid >> 6;
    const int lane = tid & 63;
    const int g    = lane >> 4;
    const int c    = lane & 15;
    const int mode = blockIdx.y;
    const long rb  = (long)blockIdx.x * 64;

    const int srow = tid >> 2;            // 0..63
    const int skq  = (tid & 3) << 4;      // 0,16,32,48
    const float* xp  = x + (rb + srow) * DDIM + skq;
    const short* whp = wbhi + mode * (HSZ * DDIM) + srow * DDIM + skq;
    const short* wlp = wblo + mode * (HSZ * DDIM) + srow * DDIM + skq;

    f32x4 acc[4];
    acc[0] = 0; acc[1] = 0; acc[2] = 0; acc[3] = 0;

    for (int k0 = 0; k0 < DDIM; k0 += 64) {
        // stage x 64x64 fp32 -> split bf16 (16 floats/thread)
        {
            float4 f0 = *(const float4*)(xp + k0);
            float4 f1 = *(const float4*)(xp + k0 + 4);
            float4 f2 = *(const float4*)(xp + k0 + 8);
            float4 f3 = *(const float4*)(xp + k0 + 12);
            float fv[16] = {f0.x,f0.y,f0.z,f0.w, f1.x,f1.y,f1.z,f1.w,
                            f2.x,f2.y,f2.z,f2.w, f3.x,f3.y,f3.z,f3.w};
            short hh[16], ll[16];
            #pragma unroll
            for (int j = 0; j < 16; ++j) split_rn(fv[j], hh[j], ll[j]);
            #pragma unroll
            for (int u = 0; u < 2; ++u) {
                *(bf16x8*)&xh[srow][skq + 8*u] = *(bf16x8*)&hh[8*u];
                *(bf16x8*)&xl[srow][skq + 8*u] = *(bf16x8*)&ll[8*u];
            }
        }
        // stage W 64x64 bf16 hi/lo (16 shorts/thread/array)
        {
            bf16x8 a0 = *(const bf16x8*)(whp + k0);
            bf16x8 a1 = *(const bf16x8*)(whp + k0 + 8);
            bf16x8 b0 = *(const bf16x8*)(wlp + k0);
            bf16x8 b1 = *(const bf16x8*)(wlp + k0 + 8);
            *(bf16x8*)&wh[srow][skq]     = a0;
            *(bf16x8*)&wh[srow][skq + 8] = a1;
            *(bf16x8*)&wl[srow][skq]     = b0;
            *(bf16x8*)&wl[srow][skq + 8] = b1;
        }
        __syncthreads();

        #pragma unroll
        for (int kk = 0; kk < 2; ++kk) {
            bf16x8 ah = *(const bf16x8*)&xh[16*wv + c][kk*32 + 8*g];
            bf16x8 al = *(const bf16x8*)&xl[16*wv + c][kk*32 + 8*g];
            __builtin_amdgcn_s_setprio(1);
            #pragma unroll
            for (int ct = 0; ct < 4; ++ct) {
                bf16x8 bh = *(const bf16x8*)&wh[ct*16 + c][kk*32 + 8*g];
                bf16x8 bl = *(const bf16x8*)&wl[ct*16 + c][kk*32 + 8*g];
                acc[ct] = MFMA16(al, bh, acc[ct]);
                acc[ct] = MFMA16(ah, bl, acc[ct]);
                acc[ct] = MFMA16(ah, bh, acc[ct]);
            }
            __builtin_amdgcn_s_setprio(0);
        }
        __syncthreads();
    }

    const int batch = (int)(rb >> 11);
    const int t0    = (int)(rb & 2047);
    if (mode < 2) {
        short* oh = mode ? qhi : khi;
        short* ol = mode ? qlo : klo;
        const float sc = mode ? 8.0f : 1.0f;   // bug-faithful *sqrt(HS) folded into q
        #pragma unroll
        for (int ct = 0; ct < 4; ++ct) {
            #pragma unroll
            for (int r = 0; r < 4; ++r) {
                long row = rb + 16*wv + 4*g + r;
                short h, lo2; split_rn(acc[ct][r] * sc, h, lo2);
                oh[row * HSZ + ct*16 + c] = h;
                ol[row * HSZ + ct*16 + c] = lo2;
            }
        }
    } else {
        // v: bf16 hi only, transpose through LDS (reuse wh)
        #pragma unroll
        for (int ct = 0; ct < 4; ++ct)
            #pragma unroll
            for (int r = 0; r < 4; ++r)
                wh[ct*16 + c][16*wv + 4*g + r] = bf16rn(acc[ct][r]);
        __syncthreads();
        const int d = tid >> 2, t16 = (tid & 3) << 4;
        long gofs = ((long)(batch * HSZ + d)) * TSEQ + t0 + t16;
        *(bf16x8*)(vthi + gofs)     = *(const bf16x8*)&wh[d][t16];
        *(bf16x8*)(vthi + gofs + 8) = *(const bf16x8*)&wh[d][t16 + 8];
    }
}

// ---------------------------------------------------------------------------
// Kernel 2: causal flash attention. grid 512 (XCD-mapped), block 512 (8 waves,
// barrier-free main loop; per-wave online softmax via swapped QK^T).
// PV is bf16 hi-only (P and V): 8 MFMA/step. P staged per-wave in stride-88
// LDS (2-way free). 3-round tree merge at the end. ~40KB LDS, VGPR<=128
// target -> 2 blocks/CU.
// ---------------------------------------------------------------------------
__global__ __launch_bounds__(512, 4) void attn_mfma(
    const short* __restrict__ qhi, const short* __restrict__ qlo,
    const short* __restrict__ khi, const short* __restrict__ klo,
    const short* __restrict__ vthi,
    float* __restrict__ out)
{
    __shared__ __align__(16) short pbuf[8][16][88];   // 22.5 KB
    __shared__ float obuf[4][16][68];                 // 17.4 KB
    __shared__ float mlbuf[8][16][2];                 // 1 KB

    const int tid  = threadIdx.x;
    const int w    = tid >> 6;
    const int lane = tid & 63;
    const int g    = lane >> 4;
    const int c    = lane & 15;

    const int bid   = blockIdx.x;
    const int work  = ((bid & 7) << 6) | (bid >> 3);   // XCD-contiguous chunks
    const int batch = work >> 7;
    const int rank  = work & 127;
    const int tile  = (rank < 64) ? (127 - 2*rank) : (126 - 2*(rank - 64));
    const int qb0   = tile << 4;
    const long bb   = (long)batch * TSEQ;
    const int lastkey = qb0 + 15;

    // Q fragments (B-operand of swapped QK^T): row = c (q-row), k = kk*32+8g+j
    bf16x8 qh[2], ql[2];
    {
        const long qofs = (bb + qb0 + c) * HSZ;
        #pragma unroll
        for (int kk = 0; kk < 2; ++kk) {
            qh[kk] = *(const bf16x8*)(qhi + qofs + kk*32 + 8*g);
            ql[kk] = *(const bf16x8*)(qlo + qofs + kk*32 + 8*g);
        }
    }

    f32x4 oacc[4];
    #pragma unroll
    for (int dt = 0; dt < 4; ++dt) oacc[dt] = 0;
    float m = -1e30f, l = 0.0f;

    if (64 * w <= lastkey) {
        const int nsteps = ((lastkey - 64 * w) >> 9) + 1;
        for (int s = 0; s < nsteps; ++s) {
            const int jb = (s << 9) + (w << 6);
            // ---- S^T = mfma(K, Q): lane -> S[qrow=c][key=jb+16t+4g+r] ----
            f32x4 sa[4];
            sa[0] = 0; sa[1] = 0; sa[2] = 0; sa[3] = 0;
            #pragma unroll
            for (int kk = 0; kk < 2; ++kk) {
                bf16x8 kb_h[4], kb_l[4];
                #pragma unroll
                for (int t = 0; t < 4; ++t) {
                    const long kofs = (bb + jb + t*16 + c) * HSZ + kk*32 + 8*g;
                    kb_h[t] = *(const bf16x8*)(khi + kofs);
                    kb_l[t] = *(const bf16x8*)(klo + kofs);
                }
                __builtin_amdgcn_s_setprio(1);
                #pragma unroll
                for (int t = 0; t < 4; ++t) {
                    sa[t] = MFMA16(kb_h[t], ql[kk], sa[t]);
                    sa[t] = MFMA16(kb_l[t], qh[kk], sa[t]);
                    sa[t] = MFMA16(kb_h[t], qh[kk], sa[t]);
                }
                __builtin_amdgcn_s_setprio(0);
            }
            // ---- V loads (hi only) — in flight during softmax ----
            bf16x8 vb[2][4];
            #pragma unroll
            for (int kk = 0; kk < 2; ++kk)
                #pragma unroll
                for (int dt = 0; dt < 4; ++dt) {
                    const long vofs = ((long)(batch * HSZ + dt*16 + c)) * TSEQ + jb + kk*32 + 8*g;
                    vb[kk][dt] = *(const bf16x8*)(vthi + vofs);
                }
            // ---- causal mask ----
            if (jb + 63 > qb0) {
                #pragma unroll
                for (int t = 0; t < 4; ++t) {
                    const int kb0 = jb + t*16 + 4*g;
                    #pragma unroll
                    for (int r = 0; r < 4; ++r)
                        if (kb0 + r > qb0 + c) sa[t][r] = -1e30f;
                }
            }
            // ---- per-lane online softmax for q-row c ----
            float mx = sa[0][0];
            #pragma unroll
            for (int t = 0; t < 4; ++t)
                #pragma unroll
                for (int r = 0; r < 4; ++r) mx = fmaxf(mx, sa[t][r]);
            mx = fmaxf(mx, __shfl_xor(mx, 16));
            mx = fmaxf(mx, __shfl_xor(mx, 32));
            const float mold = m;
            const float mn = fmaxf(mold, mx);
            float rs = 0.0f;
            #pragma unroll
            for (int t = 0; t < 4; ++t) {
                float p0 = __expf(sa[t][0] - mn);
                float p1 = __expf(sa[t][1] - mn);
                float p2 = __expf(sa[t][2] - mn);
                float p3 = __expf(sa[t][3] - mn);
                rs += (p0 + p1) + (p2 + p3);
                u32 w0 = (u32)(unsigned short)bf16rn(p0) | ((u32)(unsigned short)bf16rn(p1) << 16);
                u32 w1 = (u32)(unsigned short)bf16rn(p2) | ((u32)(unsigned short)bf16rn(p3) << 16);
                *(u32*)&pbuf[w][c][t*16 + 4*g]     = w0;
                *(u32*)&pbuf[w][c][t*16 + 4*g + 2] = w1;
            }
            rs += __shfl_xor(rs, 16);
            rs += __shfl_xor(rs, 32);
            const float fs = __expf(mold - mn);
            l = l * fs + rs;
            m = mn;
            if (__any(mn > mold)) {
                float fr[4];
                #pragma unroll
                for (int r = 0; r < 4; ++r) fr[r] = __shfl(fs, 16*g + 4*g + r);
                #pragma unroll
                for (int dt = 0; dt < 4; ++dt) {
                    oacc[dt][0] *= fr[0]; oacc[dt][1] *= fr[1];
                    oacc[dt][2] *= fr[2]; oacc[dt][3] *= fr[3];
                }
            }
            // ---- O += P V (hi-only: 8 MFMA) ----
            #pragma unroll
            for (int kk = 0; kk < 2; ++kk) {
                bf16x8 pa = *(const bf16x8*)&pbuf[w][c][kk*32 + 8*g];
                __builtin_amdgcn_s_setprio(1);
                #pragma unroll
                for (int dt = 0; dt < 4; ++dt)
                    oacc[dt] = MFMA16(pa, vb[kk][dt], oacc[dt]);
                __builtin_amdgcn_s_setprio(0);
            }
        }
    }

    // ---- merge: scale by global weights, then 3-round tree ----
    if (lane < 16) { mlbuf[w][lane][0] = m; mlbuf[w][lane][1] = l; }
    __syncthreads();
    float fw_[4], linv_[4];
    #pragma unroll
    for (int r = 0; r < 4; ++r) {
        const int row = 4*g + r;
        float ms = mlbuf[0][row][0];
        #pragma unroll
        for (int wv = 1; wv < 8; ++wv) ms = fmaxf(ms, mlbuf[wv][row][0]);
        float ls = 0.0f;
        #pragma unroll
        for (int wv = 0; wv < 8; ++wv)
            ls += __expf(mlbuf[wv][row][0] - ms) * mlbuf[wv][row][1];
        fw_[r] = __expf(mlbuf[w][row][0] - ms);
        linv_[r] = 1.0f / ls;
    }
    #pragma unroll
    for (int dt = 0; dt < 4; ++dt) {
        oacc[dt][0] *= fw_[0]; oacc[dt][1] *= fw_[1];
        oacc[dt][2] *= fw_[2]; oacc[dt][3] *= fw_[3];
    }
    // round 1: waves 4-7 -> slots 0-3
    if (w >= 4)
        #pragma unroll
        for (int dt = 0; dt < 4; ++dt)
            #pragma unroll
            for (int r = 0; r < 4; ++r)
                obuf[w-4][4*g + r][dt*16 + c] = oacc[dt][r];
    __syncthreads();
    // round 2: waves 0-3 add their slot; waves 2,3 re-publish partial sums
    if (w < 4)
        #pragma unroll
        for (int dt = 0; dt < 4; ++dt)
            #pragma unroll
            for (int r = 0; r < 4; ++r)
                oacc[dt][r] += obuf[w][4*g + r][dt*16 + c];
    if (w == 2 || w == 3)
        #pragma unroll
        for (int dt = 0; dt < 4; ++dt)
            #pragma unroll
            for (int r = 0; r < 4; ++r)
                obuf[w][4*g + r][dt*16 + c] = oacc[dt][r];
    __syncthreads();
    // round 3: w0 += slot2; w1 += slot3 and publishes to slot1
    if (w == 0)
        #pragma unroll
        for (int dt = 0; dt < 4; ++dt)
            #pragma unroll
            for (int r = 0; r < 4; ++r)
                oacc[dt][r] += obuf[2][4*g + r][dt*16 + c];
    if (w == 1) {
        #pragma unroll
        for (int dt = 0; dt < 4; ++dt)
            #pragma unroll
            for (int r = 0; r < 4; ++r) {
                oacc[dt][r] += obuf[3][4*g + r][dt*16 + c];
                obuf[1][4*g + r][dt*16 + c] = oacc[dt][r];
            }
    }
    __syncthreads();
    if (w == 0) {
        #pragma unroll
        for (int dt = 0; dt < 4; ++dt)
            #pragma unroll
            for (int r = 0; r < 4; ++r) {
                float val = (oacc[dt][r] + obuf[1][4*g + r][dt*16 + c]) * linv_[r];
                out[(bb + qb0 + 4*g + r) * HSZ + dt*16 + c] = val;
            }
    }
}

// ---------------------------------------------------------------------------
extern "C" void kernel_launch(void* const* d_in, const int* in_sizes, int n_in,
                              void* d_out, int out_size, void* d_ws, size_t ws_size,
                              hipStream_t stream) {
    const float* x  = (const float*)d_in[0];
    const float* Wk = (const float*)d_in[1];
    const float* Wq = (const float*)d_in[2];
    const float* Wv = (const float*)d_in[3];
    float* out = (float*)d_out;

    short* ws = (short*)d_ws;
    const size_t SEG = (size_t)NROWS * HSZ;   // 524288 elements
    short* khi  = ws;
    short* klo  = ws + SEG;
    short* qhi  = ws + 2*SEG;
    short* qlo  = ws + 3*SEG;
    short* vthi = ws + 4*SEG;                 // [4*64][2048] bf16 (hi only)
    short* wbhi = ws + 5*SEG;                 // [3*64][1024]
    short* wblo = wbhi + 3*HSZ*DDIM;

    wsplit_kernel<<<192, 256, 0, stream>>>(Wk, Wq, Wv, wbhi, wblo);
    proj_mfma<<<dim3(128, 3), 256, 0, stream>>>(x, wbhi, wblo,
                                                khi, klo, qhi, qlo, vthi);
    attn_mfma<<<512, 512, 0, stream>>>(qhi, qlo, khi, klo, vthi, out);
}

// Round 7
// 132.250 us; speedup vs baseline: 1.2767x; 1.0254x over previous
//
#include <hip/hip_runtime.h>

#define TSEQ 2048
#define DDIM 1024
#define HSZ  64
#define NB   4
#define NROWS (NB * TSEQ)

typedef short bf16x8 __attribute__((ext_vector_type(8)));
typedef short s16x4  __attribute__((ext_vector_type(4)));
typedef float f32x4  __attribute__((ext_vector_type(4)));
typedef unsigned int u32;

#define MFMA16(a, b, c) __builtin_amdgcn_mfma_f32_16x16x32_bf16((a), (b), (c), 0, 0, 0)

// fp32 -> bf16 hi (RN) + bf16 lo (residual)
__device__ inline void split_rn(float f, short& hi, short& lo) {
    u32 u = __builtin_bit_cast(u32, f);
    u32 rr = (u + 0x7fffu + ((u >> 16) & 1u)) & 0xffff0000u;
    hi = (short)(rr >> 16);
    float fh = __builtin_bit_cast(float, rr);
    float fl = f - fh;
    lo = (short)(__builtin_bit_cast(u32, fl) >> 16);
}
__device__ inline short bf16rn(float f) {
    u32 u = __builtin_bit_cast(u32, f);
    return (short)((u + 0x7fffu + ((u >> 16) & 1u)) >> 16);
}

// ---------------------------------------------------------------------------
// Kernel 0: split W (fp32 [3*64][1024]) -> bf16 hi/lo [192][1024].
// ---------------------------------------------------------------------------
__global__ __launch_bounds__(256) void wsplit_kernel(
    const float* __restrict__ Wk, const float* __restrict__ Wq, const float* __restrict__ Wv,
    short* __restrict__ wbhi, short* __restrict__ wblo)
{
    int i = blockIdx.x * 256 + threadIdx.x;
    int off = i << 2;
    int which = off >> 16;
    int loc = off & 65535;
    const float* src = (which == 0) ? Wk : (which == 1) ? Wq : Wv;
    float4 v = *(const float4*)(src + loc);
    short h0,h1,h2,h3, l0,l1,l2,l3;
    split_rn(v.x, h0, l0); split_rn(v.y, h1, l1);
    split_rn(v.z, h2, l2); split_rn(v.w, h3, l3);
    *(s16x4*)(wbhi + off) = (s16x4){h0,h1,h2,h3};
    *(s16x4*)(wblo + off) = (s16x4){l0,l1,l2,l3};
}

// ---------------------------------------------------------------------------
// Kernel 1: QKV projection, BM=64, grid (128,3), 256 thr (4 waves).
// Register-prefetch pipeline: K-step t+1's x/W global loads are issued right
// after barrier B1 so they are in flight under step t's MFMA phase (T14).
// LDS 45KB stride-88 rows -> 3 blocks/CU. v output: bf16 hi only, transposed.
// ---------------------------------------------------------------------------
__global__ __launch_bounds__(256, 3) void proj_mfma(
    const float* __restrict__ x,
    const short* __restrict__ wbhi, const short* __restrict__ wblo,
    short* __restrict__ khi, short* __restrict__ klo,
    short* __restrict__ qhi, short* __restrict__ qlo,
    short* __restrict__ vthi)
{
    __shared__ __align__(16) short xh[64][88], xl[64][88];
    __shared__ __align__(16) short wh[64][88], wl[64][88];

    const int tid  = threadIdx.x;
    const int wv   = tid >> 6;
    const int lane = tid & 63;
    const int g    = lane >> 4;
    const int c    = lane & 15;
    const int mode = blockIdx.y;
    const long rb  = (long)blockIdx.x * 64;

    const int srow = tid >> 2;            // 0..63
    const int skq  = (tid & 3) << 4;      // 0,16,32,48
    const float* xp  = x + (rb + srow) * DDIM + skq;
    const short* whp = wbhi + mode * (HSZ * DDIM) + srow * DDIM + skq;
    const short* wlp = wblo + mode * (HSZ * DDIM) + srow * DDIM + skq;

    f32x4 acc[4];
    acc[0] = 0; acc[1] = 0; acc[2] = 0; acc[3] = 0;

    // preload K-step 0 into registers
    float4 f0 = *(const float4*)(xp);
    float4 f1 = *(const float4*)(xp + 4);
    float4 f2 = *(const float4*)(xp + 8);
    float4 f3 = *(const float4*)(xp + 12);
    bf16x8 a0 = *(const bf16x8*)(whp);
    bf16x8 a1 = *(const bf16x8*)(whp + 8);
    bf16x8 b0 = *(const bf16x8*)(wlp);
    bf16x8 b1 = *(const bf16x8*)(wlp + 8);

    for (int k0 = 0; k0 < DDIM; k0 += 64) {
        // split x regs and store staged tile to LDS
        {
            float fv[16] = {f0.x,f0.y,f0.z,f0.w, f1.x,f1.y,f1.z,f1.w,
                            f2.x,f2.y,f2.z,f2.w, f3.x,f3.y,f3.z,f3.w};
            short hh[16], ll[16];
            #pragma unroll
            for (int j = 0; j < 16; ++j) split_rn(fv[j], hh[j], ll[j]);
            *(bf16x8*)&xh[srow][skq]     = *(bf16x8*)&hh[0];
            *(bf16x8*)&xh[srow][skq + 8] = *(bf16x8*)&hh[8];
            *(bf16x8*)&xl[srow][skq]     = *(bf16x8*)&ll[0];
            *(bf16x8*)&xl[srow][skq + 8] = *(bf16x8*)&ll[8];
            *(bf16x8*)&wh[srow][skq]     = a0;
            *(bf16x8*)&wh[srow][skq + 8] = a1;
            *(bf16x8*)&wl[srow][skq]     = b0;
            *(bf16x8*)&wl[srow][skq + 8] = b1;
        }
        __syncthreads();                       // B1: tiles ready

        // issue next K-step's global loads (in flight during MFMA)
        if (k0 + 64 < DDIM) {
            const int kn = k0 + 64;
            f0 = *(const float4*)(xp + kn);
            f1 = *(const float4*)(xp + kn + 4);
            f2 = *(const float4*)(xp + kn + 8);
            f3 = *(const float4*)(xp + kn + 12);
            a0 = *(const bf16x8*)(whp + kn);
            a1 = *(const bf16x8*)(whp + kn + 8);
            b0 = *(const bf16x8*)(wlp + kn);
            b1 = *(const bf16x8*)(wlp + kn + 8);
        }

        #pragma unroll
        for (int kk = 0; kk < 2; ++kk) {
            bf16x8 ah = *(const bf16x8*)&xh[16*wv + c][kk*32 + 8*g];
            bf16x8 al = *(const bf16x8*)&xl[16*wv + c][kk*32 + 8*g];
            __builtin_amdgcn_s_setprio(1);
            #pragma unroll
            for (int ct = 0; ct < 4; ++ct) {
                bf16x8 bh = *(const bf16x8*)&wh[ct*16 + c][kk*32 + 8*g];
                bf16x8 bl = *(const bf16x8*)&wl[ct*16 + c][kk*32 + 8*g];
                acc[ct] = MFMA16(al, bh, acc[ct]);
                acc[ct] = MFMA16(ah, bl, acc[ct]);
                acc[ct] = MFMA16(ah, bh, acc[ct]);
            }
            __builtin_amdgcn_s_setprio(0);
        }
        __syncthreads();                       // B2: safe to overwrite tiles
    }

    const int batch = (int)(rb >> 11);
    const int t0    = (int)(rb & 2047);
    if (mode < 2) {
        short* oh = mode ? qhi : khi;
        short* ol = mode ? qlo : klo;
        const float sc = mode ? 8.0f : 1.0f;   // bug-faithful *sqrt(HS) folded into q
        #pragma unroll
        for (int ct = 0; ct < 4; ++ct) {
            #pragma unroll
            for (int r = 0; r < 4; ++r) {
                long row = rb + 16*wv + 4*g + r;
                short h, lo2; split_rn(acc[ct][r] * sc, h, lo2);
                oh[row * HSZ + ct*16 + c] = h;
                ol[row * HSZ + ct*16 + c] = lo2;
            }
        }
    } else {
        // v: bf16 hi only, transpose through LDS (reuse wh)
        #pragma unroll
        for (int ct = 0; ct < 4; ++ct)
            #pragma unroll
            for (int r = 0; r < 4; ++r)
                wh[ct*16 + c][16*wv + 4*g + r] = bf16rn(acc[ct][r]);
        __syncthreads();
        const int d = tid >> 2, t16 = (tid & 3) << 4;
        long gofs = ((long)(batch * HSZ + d)) * TSEQ + t0 + t16;
        *(bf16x8*)(vthi + gofs)     = *(const bf16x8*)&wh[d][t16];
        *(bf16x8*)(vthi + gofs + 8) = *(const bf16x8*)&wh[d][t16 + 8];
    }
}

// ---------------------------------------------------------------------------
// Kernel 2: causal flash attention. grid 512 (XCD-mapped), block 512 (8 waves,
// barrier-free main loop; per-wave online softmax via swapped QK^T).
// SLIM register version: K hi/lo loaded per-kk (transient), V hi-only loaded
// inside the PV kk-loop, P through per-wave LDS. Live set ~100 VGPR -> fits
// the launch_bounds(512,4) cap of 128 WITHOUT spilling (R4-R6 spilled here).
// obuf aliases pbuf (LDS 24KB total).
// ---------------------------------------------------------------------------
__global__ __launch_bounds__(512, 4) void attn_mfma(
    const short* __restrict__ qhi, const short* __restrict__ qlo,
    const short* __restrict__ khi, const short* __restrict__ klo,
    const short* __restrict__ vthi,
    float* __restrict__ out)
{
    __shared__ __align__(16) char smem[22528];        // pbuf / obuf union
    short (*pbuf)[16][88] = (short(*)[16][88])smem;   // [8][16][88] bf16
    float (*obuf)[16][68] = (float(*)[16][68])smem;   // [4][16][68] f32 (merge)
    __shared__ float mlbuf[8][16][2];

    const int tid  = threadIdx.x;
    const int w    = tid >> 6;
    const int lane = tid & 63;
    const int g    = lane >> 4;
    const int c    = lane & 15;

    const int bid   = blockIdx.x;
    const int work  = ((bid & 7) << 6) | (bid >> 3);   // XCD-contiguous chunks
    const int batch = work >> 7;
    const int rank  = work & 127;
    const int tile  = (rank < 64) ? (127 - 2*rank) : (126 - 2*(rank - 64));
    const int qb0   = tile << 4;
    const long bb   = (long)batch * TSEQ;
    const int lastkey = qb0 + 15;

    // Q fragments (B-operand of swapped QK^T): row = c (q-row), k = kk*32+8g+j
    bf16x8 qh[2], ql[2];
    {
        const long qofs = (bb + qb0 + c) * HSZ;
        #pragma unroll
        for (int kk = 0; kk < 2; ++kk) {
            qh[kk] = *(const bf16x8*)(qhi + qofs + kk*32 + 8*g);
            ql[kk] = *(const bf16x8*)(qlo + qofs + kk*32 + 8*g);
        }
    }

    f32x4 oacc[4];
    #pragma unroll
    for (int dt = 0; dt < 4; ++dt) oacc[dt] = 0;
    float m = -1e30f, l = 0.0f;

    if (64 * w <= lastkey) {
        const int nsteps = ((lastkey - 64 * w) >> 9) + 1;
        for (int s = 0; s < nsteps; ++s) {
            const int jb = (s << 9) + (w << 6);
            // ---- S^T = mfma(K, Q): lane -> S[qrow=c][key=jb+16t+4g+r] ----
            f32x4 sa[4];
            sa[0] = 0; sa[1] = 0; sa[2] = 0; sa[3] = 0;
            #pragma unroll
            for (int kk = 0; kk < 2; ++kk) {
                bf16x8 kb_h[4], kb_l[4];
                #pragma unroll
                for (int t = 0; t < 4; ++t) {
                    const long kofs = (bb + jb + t*16 + c) * HSZ + kk*32 + 8*g;
                    kb_h[t] = *(const bf16x8*)(khi + kofs);
                    kb_l[t] = *(const bf16x8*)(klo + kofs);
                }
                __builtin_amdgcn_s_setprio(1);
                #pragma unroll
                for (int t = 0; t < 4; ++t) {
                    sa[t] = MFMA16(kb_h[t], ql[kk], sa[t]);
                    sa[t] = MFMA16(kb_l[t], qh[kk], sa[t]);
                    sa[t] = MFMA16(kb_h[t], qh[kk], sa[t]);
                }
                __builtin_amdgcn_s_setprio(0);
            }
            // ---- causal mask ----
            if (jb + 63 > qb0) {
                #pragma unroll
                for (int t = 0; t < 4; ++t) {
                    const int kb0 = jb + t*16 + 4*g;
                    #pragma unroll
                    for (int r = 0; r < 4; ++r)
                        if (kb0 + r > qb0 + c) sa[t][r] = -1e30f;
                }
            }
            // ---- per-lane online softmax for q-row c ----
            float mx = sa[0][0];
            #pragma unroll
            for (int t = 0; t < 4; ++t)
                #pragma unroll
                for (int r = 0; r < 4; ++r) mx = fmaxf(mx, sa[t][r]);
            mx = fmaxf(mx, __shfl_xor(mx, 16));
            mx = fmaxf(mx, __shfl_xor(mx, 32));
            const float mold = m;
            const float mn = fmaxf(mold, mx);
            float rs = 0.0f;
            #pragma unroll
            for (int t = 0; t < 4; ++t) {
                float p0 = __expf(sa[t][0] - mn);
                float p1 = __expf(sa[t][1] - mn);
                float p2 = __expf(sa[t][2] - mn);
                float p3 = __expf(sa[t][3] - mn);
                rs += (p0 + p1) + (p2 + p3);
                u32 w0 = (u32)(unsigned short)bf16rn(p0) | ((u32)(unsigned short)bf16rn(p1) << 16);
                u32 w1 = (u32)(unsigned short)bf16rn(p2) | ((u32)(unsigned short)bf16rn(p3) << 16);
                *(u32*)&pbuf[w][c][t*16 + 4*g]     = w0;
                *(u32*)&pbuf[w][c][t*16 + 4*g + 2] = w1;
            }
            rs += __shfl_xor(rs, 16);
            rs += __shfl_xor(rs, 32);
            const float fs = __expf(mold - mn);
            l = l * fs + rs;
            m = mn;
            if (__any(mn > mold)) {
                float fr[4];
                #pragma unroll
                for (int r = 0; r < 4; ++r) fr[r] = __shfl(fs, 20*g + r);
                #pragma unroll
                for (int dt = 0; dt < 4; ++dt) {
                    oacc[dt][0] *= fr[0]; oacc[dt][1] *= fr[1];
                    oacc[dt][2] *= fr[2]; oacc[dt][3] *= fr[3];
                }
            }
            // ---- O += P V (hi-only; V loaded per-kk, transient) ----
            #pragma unroll
            for (int kk = 0; kk < 2; ++kk) {
                bf16x8 pa = *(const bf16x8*)&pbuf[w][c][kk*32 + 8*g];
                bf16x8 vb[4];
                #pragma unroll
                for (int dt = 0; dt < 4; ++dt) {
                    const long vofs = ((long)(batch * HSZ + dt*16 + c)) * TSEQ + jb + kk*32 + 8*g;
                    vb[dt] = *(const bf16x8*)(vthi + vofs);
                }
                __builtin_amdgcn_s_setprio(1);
                #pragma unroll
                for (int dt = 0; dt < 4; ++dt)
                    oacc[dt] = MFMA16(pa, vb[dt], oacc[dt]);
                __builtin_amdgcn_s_setprio(0);
            }
        }
    }

    // ---- merge: scale by global weights, then 3-round tree ----
    if (lane < 16) { mlbuf[w][lane][0] = m; mlbuf[w][lane][1] = l; }
    __syncthreads();
    float fw_[4], linv_[4];
    #pragma unroll
    for (int r = 0; r < 4; ++r) {
        const int row = 4*g + r;
        float ms = mlbuf[0][row][0];
        #pragma unroll
        for (int wv = 1; wv < 8; ++wv) ms = fmaxf(ms, mlbuf[wv][row][0]);
        float ls = 0.0f;
        #pragma unroll
        for (int wv = 0; wv < 8; ++wv)
            ls += __expf(mlbuf[wv][row][0] - ms) * mlbuf[wv][row][1];
        fw_[r] = __expf(mlbuf[w][row][0] - ms);
        linv_[r] = 1.0f / ls;
    }
    #pragma unroll
    for (int dt = 0; dt < 4; ++dt) {
        oacc[dt][0] *= fw_[0]; oacc[dt][1] *= fw_[1];
        oacc[dt][2] *= fw_[2]; oacc[dt][3] *= fw_[3];
    }
    __syncthreads();   // pbuf -> obuf reuse boundary
    // round 1: waves 4-7 -> slots 0-3
    if (w >= 4)
        #pragma unroll
        for (int dt = 0; dt < 4; ++dt)
            #pragma unroll
            for (int r = 0; r < 4; ++r)
                obuf[w-4][4*g + r][dt*16 + c] = oacc[dt][r];
    __syncthreads();
    // round 2: waves 0-3 add their slot; waves 2,3 re-publish partial sums
    if (w < 4)
        #pragma unroll
        for (int dt = 0; dt < 4; ++dt)
            #pragma unroll
            for (int r = 0; r < 4; ++r)
                oacc[dt][r] += obuf[w][4*g + r][dt*16 + c];
    __syncthreads();
    if (w == 2 || w == 3)
        #pragma unroll
        for (int dt = 0; dt < 4; ++dt)
            #pragma unroll
            for (int r = 0; r < 4; ++r)
                obuf[w][4*g + r][dt*16 + c] = oacc[dt][r];
    __syncthreads();
    // round 3: w0 += slot2; w1 += slot3 and publishes to slot1
    if (w == 0)
        #pragma unroll
        for (int dt = 0; dt < 4; ++dt)
            #pragma unroll
            for (int r = 0; r < 4; ++r)
                oacc[dt][r] += obuf[2][4*g + r][dt*16 + c];
    if (w == 1) {
        #pragma unroll
        for (int dt = 0; dt < 4; ++dt)
            #pragma unroll
            for (int r = 0; r < 4; ++r) {
                oacc[dt][r] += obuf[3][4*g + r][dt*16 + c];
                obuf[1][4*g + r][dt*16 + c] = oacc[dt][r];
            }
    }
    __syncthreads();
    if (w == 0) {
        #pragma unroll
        for (int dt = 0; dt < 4; ++dt)
            #pragma unroll
            for (int r = 0; r < 4; ++r) {
                float val = (oacc[dt][r] + obuf[1][4*g + r][dt*16 + c]) * linv_[r];
                out[(bb + qb0 + 4*g + r) * HSZ + dt*16 + c] = val;
            }
    }
}

// ---------------------------------------------------------------------------
extern "C" void kernel_launch(void* const* d_in, const int* in_sizes, int n_in,
                              void* d_out, int out_size, void* d_ws, size_t ws_size,
                              hipStream_t stream) {
    const float* x  = (const float*)d_in[0];
    const float* Wk = (const float*)d_in[1];
    const float* Wq = (const float*)d_in[2];
    const float* Wv = (const float*)d_in[3];
    float* out = (float*)d_out;

    short* ws = (short*)d_ws;
    const size_t SEG = (size_t)NROWS * HSZ;   // 524288 elements
    short* khi  = ws;
    short* klo  = ws + SEG;
    short* qhi  = ws + 2*SEG;
    short* qlo  = ws + 3*SEG;
    short* vthi = ws + 4*SEG;                 // [4*64][2048] bf16 (hi only)
    short* wbhi = ws + 5*SEG;                 // [3*64][1024]
    short* wblo = wbhi + 3*HSZ*DDIM;

    wsplit_kernel<<<192, 256, 0, stream>>>(Wk, Wq, Wv, wbhi, wblo);
    proj_mfma<<<dim3(128, 3), 256, 0, stream>>>(x, wbhi, wblo,
                                                khi, klo, qhi, qlo, vthi);
    attn_mfma<<<512, 512, 0, stream>>>(qhi, qlo, khi, klo, vthi, out);
}